// Round 6
// baseline (719.392 us; speedup 1.0000x reference)
//
#include <hip/hip_runtime.h>

// Problem constants: B=2, C=96, D=H=W=40, S=64000, NH=4, HD=24, L=40
// Exact simplifications vs reference:
//  - pos_attn branch dropped (softmax row-shift invariance)
//  - R6 rotations dropped (R orthogonal; (Rq).(Rk) = q.k; v unrotated)
//  - mod1@ (lp2@B + b2) + b1 folded to W'@B + b'  (W' = mod1@lp2, exact)
// Round 7: conv3 XCD swizzle (L2-resident gather): FETCH 62->16.5MB, 131->120us.
// Rounds 8-10 (reverted): occupancy / A-coalescing / full-LDS-staging all lost;
// stats+gelu fusion cost ~60us in the rest (kept unfused).
// Round 11: attn XCD swizzle neutral (kept); conv3 reproduced 119-120us.
// Round 12 model: conv3 is L1/TA LINE-REQUEST-rate bound (~1 line/cy/CU):
// A(L1-hit) + B(L2) multi-line requests ~160 lines/j-iter -> ~84us floor.
// v6: A staged in LDS (double-buffered, 1 barrier/tap, 2 blocks/CU, 208B-pad
// rows = 2-way only) -> A leaves the TA path; B unchanged. ~64 lines/j-iter.
// Also: k_zero folded into k_cvt_w, k_finalize folded into k_ng16 (-3 launches).

typedef __attribute__((ext_vector_type(8))) _Float16 half8;
typedef __attribute__((ext_vector_type(2))) _Float16 half2;
typedef __attribute__((ext_vector_type(16))) float floatx16;

static __device__ __forceinline__ half2 h2(unsigned int u) {
    return __builtin_bit_cast(half2, u);
}
static __device__ __forceinline__ float fdot2(unsigned int a, unsigned int b, float c) {
    return __builtin_amdgcn_fdot2(h2(a), h2(b), c, false);
}

// ---------------- prep: pos fp32 [b][c][s] -> f16 [b][s][c], XCD-aligned ----------------
// grid 2016: exact inverse of conv3's bijective 500-map; q = 64-s quarter of
// the 256-s conv tile. in_t is first-touch resident on the consuming XCD.
__global__ __launch_bounds__(256) void k_cvt_in(const float* __restrict__ pos,
                                                _Float16* __restrict__ in_t) {
    __shared__ _Float16 lds[64][97];
    int bid = blockIdx.x;
    int xcd = bid & 7, k = bid >> 3;      // k 0..251
    int L;
    if (xcd < 4) L = xcd * 63 + (k >> 2);
    else { if (k >= 248) return; L = 252 + (xcd - 4) * 62 + (k >> 2); }
    int q = k & 3;
    int b = L / 250;
    int s0 = (L % 250) * 256 + q * 64;
    int t = threadIdx.x;
    for (int i = t; i < 6144; i += 256) {
        int c = i / 64, sl = i % 64;
        lds[sl][c] = (_Float16)pos[(b * 96 + c) * 64000 + s0 + sl];
    }
    __syncthreads();
    _Float16* outp = in_t + ((size_t)b * 64000 + s0) * 96;
    for (int i = t; i < 6144; i += 256) {
        int sl = i / 96, c = i % 96;
        outp[i] = lds[sl][c];
    }
}

// ---------------- prep: lp1_w [o][c][tap] -> f16 wf [tap][o][c]; block 0 zeroes raw ----------------
__global__ void k_cvt_w(const float* __restrict__ w, _Float16* __restrict__ wf,
                        float* __restrict__ raw) {
    int i = blockIdx.x * 256 + threadIdx.x;
    if (i < 248832) {
        int c = i % 96, m = (i / 96) % 96, tap = i / 9216;
        wf[i] = (_Float16)w[(m * 96 + c) * 27 + tap];
    }
    if (blockIdx.x == 0) {
        for (int u = threadIdx.x; u < 768; u += 256) raw[u] = 0.f;
    }
}

// ---------------- prep: f32 -> f16 straight copy ----------------
__global__ void k_cvt_f16(const float* __restrict__ w, _Float16* __restrict__ o, int n) {
    int i = blockIdx.x * 256 + threadIdx.x;
    if (i < n) o[i] = (_Float16)w[i];
}

// ---------------- prep: W' = mod1_w @ lp2_w (f16), b' = mod1_w @ lp2_b + mod1_b ----------------
__global__ __launch_bounds__(256) void k_fold(const float* __restrict__ lp2_w,
                                              const float* __restrict__ lp2_b,
                                              const float* __restrict__ mod1_w,
                                              const float* __restrict__ mod1_b,
                                              _Float16* __restrict__ wfold,
                                              float* __restrict__ bfold) {
    int i = blockIdx.x * 256 + threadIdx.x;   // grid 36 -> 9216 outputs
    if (i < 9216) {
        int o = i / 96, c = i % 96;
        float a = 0.f;
        for (int k = 0; k < 96; k++) a += mod1_w[o * 96 + k] * lp2_w[k * 96 + c];
        wfold[i] = (_Float16)a;
    }
    if (blockIdx.x == 0 && threadIdx.x < 96) {
        int o = threadIdx.x;
        float a = mod1_b[o];
        for (int k = 0; k < 96; k++) a += mod1_w[o * 96 + k] * lp2_b[k];
        bfold[o] = a;
    }
}

// ---------------- conv 3x3x3 circular: v2 + A-operand via double-buffered LDS ----------------
// A (18KB/tap, shared by 4 waves) staged global->reg->LDS, 1 barrier/tap.
// ds_read_b128 with 208B row pitch (2-way conflict only). B stays the per-lane
// L2-local gather (XCD swizzle). TA line-requests drop ~160 -> ~64 per j-iter.
__global__ __launch_bounds__(256) void k_conv3_v6(const _Float16* __restrict__ in_t,
                                                  const _Float16* __restrict__ wf,  // [tap][m][c]
                                                  const float* __restrict__ bias,
                                                  _Float16* __restrict__ c3) {
    // smem: tbl int[27*256] @0 (27648) | A dbuf 2 x [96 x 208B] @27648 (39936)
    //       | bsh float[96] @67584 (384). Epilogue: st f16[256*98] @0 (50176).
    __shared__ __align__(16) char smem[67968];
    int* tbl = (int*)smem;
    char* Abuf = smem + 27648;
    float* bsh = (float*)(smem + 67584);
    _Float16* st = (_Float16*)smem;

    int t = threadIdx.x;
    int bid = blockIdx.x;
    {   // bijective XCD-chunked remap (nwg=500: q=62, r=4)
        int xcd = bid & 7, idx = bid >> 3;
        bid = (xcd < 4) ? (xcd * 63 + idx) : (252 + (xcd - 4) * 62 + idx);
    }
    int b = bid / 250;
    int s0 = (bid % 250) * 256;

    for (int u = t; u < 27 * 256; u += 256) {
        int tap = u >> 8, nl = u & 255;
        int kd = tap / 9, kh = (tap / 3) % 3, kw = tap % 3;
        int s = s0 + nl;
        int d = s / 1600, r = s - d * 1600;
        int h = r / 40, w = r - h * 40;
        int ds = d + kd - 1; if (ds < 0) ds += 40; else if (ds >= 40) ds -= 40;
        int hs = h + kh - 1; if (hs < 0) hs += 40; else if (hs >= 40) hs -= 40;
        int wv2 = w + kw - 1; if (wv2 < 0) wv2 += 40; else if (wv2 >= 40) wv2 -= 40;
        tbl[u] = ((ds * 1600 + hs * 40 + wv2) * 96) * 2;   // byte offset in batch slab
    }
    if (t < 96) bsh[t] = bias[t];

    // prologue: stage A tap 0 into buf 0 (1152 uint4, row-padded to 208B)
    {
        const uint4* asrc = (const uint4*)wf;
#pragma unroll
        for (int k = 0; k < 5; k++) {
            int i = k * 256 + t;
            if (i < 1152) {
                uint4 v = asrc[i];
                *(uint4*)(Abuf + (i / 12) * 208 + (i % 12) * 16) = v;
            }
        }
    }
    __syncthreads();

    int wv = t >> 6, lane = t & 63;
    int n31 = lane & 31, kg = lane >> 5;
    const char* inb = (const char*)(in_t + (size_t)b * 64000 * 96) + kg * 16;

    floatx16 acc[3][2];
#pragma unroll
    for (int mt = 0; mt < 3; mt++)
#pragma unroll
        for (int nt = 0; nt < 2; nt++)
#pragma unroll
            for (int r = 0; r < 16; r++) acc[mt][nt][r] = 0.f;

    for (int tap = 0; tap < 27; tap++) {
        int cur = tap & 1;
        uint4 rA[5];
        if (tap < 26) {   // issue next tap's A loads early (latency hides under MFMA)
            const uint4* asrc = (const uint4*)(wf + (tap + 1) * 9216);
#pragma unroll
            for (int k = 0; k < 5; k++) {
                int i = k * 256 + t;
                if (i < 1152) rA[k] = asrc[i];
            }
        }
        int ta0 = tbl[tap * 256 + wv * 64 + n31];
        int ta1 = tbl[tap * 256 + wv * 64 + 32 + n31];
        const char* pb0 = inb + ta0;
        const char* pb1 = inb + ta1;
        const char* Ac = Abuf + cur * 19968 + n31 * 208 + kg * 16;
#pragma unroll
        for (int j = 0; j < 6; j++) {
            half8 b0 = *(const half8*)(pb0 + j * 32);
            half8 b1 = *(const half8*)(pb1 + j * 32);
            half8 a0 = *(const half8*)(Ac + j * 32);
            half8 a1 = *(const half8*)(Ac + 32 * 208 + j * 32);
            half8 a2 = *(const half8*)(Ac + 64 * 208 + j * 32);
            acc[0][0] = __builtin_amdgcn_mfma_f32_32x32x16_f16(a0, b0, acc[0][0], 0, 0, 0);
            acc[0][1] = __builtin_amdgcn_mfma_f32_32x32x16_f16(a0, b1, acc[0][1], 0, 0, 0);
            acc[1][0] = __builtin_amdgcn_mfma_f32_32x32x16_f16(a1, b0, acc[1][0], 0, 0, 0);
            acc[1][1] = __builtin_amdgcn_mfma_f32_32x32x16_f16(a1, b1, acc[1][1], 0, 0, 0);
            acc[2][0] = __builtin_amdgcn_mfma_f32_32x32x16_f16(a2, b0, acc[2][0], 0, 0, 0);
            acc[2][1] = __builtin_amdgcn_mfma_f32_32x32x16_f16(a2, b1, acc[2][1], 0, 0, 0);
        }
        if (tap < 26) {   // write next buffer (region idle since last barrier)
            char* Anx = Abuf + (cur ^ 1) * 19968;
#pragma unroll
            for (int k = 0; k < 5; k++) {
                int i = k * 256 + t;
                if (i < 1152) *(uint4*)(Anx + (i / 12) * 208 + (i % 12) * 16) = rA[k];
            }
        }
        __syncthreads();
    }

    // epilogue: padded transpose (st overlays tbl/Abuf; safe after final barrier)
#pragma unroll
    for (int mt = 0; mt < 3; mt++)
#pragma unroll
        for (int nt = 0; nt < 2; nt++)
#pragma unroll
            for (int r = 0; r < 16; r++) {
                int m = mt * 32 + (r & 3) + 8 * (r >> 2) + 4 * kg;
                int sl = wv * 64 + nt * 32 + n31;
                st[sl * 98 + m] = (_Float16)(acc[mt][nt][r] + bsh[m]);
            }
    __syncthreads();

    unsigned int* dst = (unsigned int*)(c3 + ((size_t)(b * 64000 + s0)) * 96);
    for (int i = t; i < 12288; i += 256) {
        int row = i / 48, sg = i % 48;
        dst[i] = *(const unsigned int*)&st[row * 98 + sg * 2];
    }
}

// ---------------- per-(b,c) stats over f16 [b][s][96]: atomic partial sums ----------------
__global__ __launch_bounds__(192) void k_stats_sc(const _Float16* __restrict__ in,
                                                  float* __restrict__ raw) {   // [192][2]
    __shared__ float red_s[16][96], red_q[16][96];
    int bid = blockIdx.x;            // 100 blocks: b = bid/50, chunk of 1280 s
    int b = bid / 50, ch = bid % 50;
    int t = threadIdx.x;
    int sp = t / 12, cs = t % 12;
    const uint4* base = (const uint4*)(in + ((size_t)(b * 64000 + ch * 1280)) * 96);
    float s8[8], q8[8];
#pragma unroll
    for (int e = 0; e < 8; e++) { s8[e] = 0.f; q8[e] = 0.f; }
    for (int i = 0; i < 80; i++) {
        uint4 v = base[(sp + i * 16) * 12 + cs];
        half8 h = __builtin_bit_cast(half8, v);
#pragma unroll
        for (int e = 0; e < 8; e++) { float f = (float)h[e]; s8[e] += f; q8[e] += f * f; }
    }
#pragma unroll
    for (int e = 0; e < 8; e++) { red_s[sp][cs * 8 + e] = s8[e]; red_q[sp][cs * 8 + e] = q8[e]; }
    __syncthreads();
    if (t < 96) {
        float S = 0.f, Q = 0.f;
        for (int k = 0; k < 16; k++) { S += red_s[k][t]; Q += red_q[k][t]; }
        atomicAdd(&raw[(b * 96 + t) * 2], S);
        atomicAdd(&raw[(b * 96 + t) * 2 + 1], Q);
    }
}

// ---------------- norm + exact gelu on f16 [b][s][96], in-place; finalize fused ----------------
__global__ __launch_bounds__(256) void k_ng16(_Float16* __restrict__ x, const float* __restrict__ raw) {
    __shared__ float2 sfs[192];
    int t = threadIdx.x, bid = blockIdx.x;
    if (t < 192) {
        float S = raw[t * 2], Q = raw[t * 2 + 1];
        float mu = S * (1.f / 64000.f);
        float var = Q * (1.f / 64000.f) - mu * mu;
        sfs[t] = make_float2(mu, rsqrtf(var + 1e-5f));
    }
    __syncthreads();
    uint4* p = (uint4*)x;
#pragma unroll
    for (int k = 0; k < 4; k++) {
        int i = bid * 1024 + k * 256 + t;      // uint4 index, 1,536,000 total
        int e0 = i * 8;
        int b = e0 / 6144000;
        int c0 = e0 % 96;
        const float2* sp = &sfs[b * 96 + c0];
        uint4 v = p[i];
        half8 h = __builtin_bit_cast(half8, v);
        _Float16 o[8];
#pragma unroll
        for (int e = 0; e < 8; e++) {
            float2 st = sp[e];
            float u = ((float)h[e] - st.x) * st.y;
            o[e] = (_Float16)(0.5f * u * (1.f + erff(u * 0.70710678118654752f)));
        }
        p[i] = *(uint4*)o;
    }
}

// ---------------- 96x96 f16 MFMA GEMM on [b][s][96]; MODE 1: sigmoid * x epilogue ----------------
template <int MODE>
__global__ __launch_bounds__(256) void k_gemm96(const _Float16* __restrict__ in,
                                                const _Float16* __restrict__ w,   // [96][96]
                                                const float* __restrict__ bias,
                                                const float* __restrict__ xg,     // [b][c][s] f32 (MODE 1)
                                                _Float16* __restrict__ outp) {
    __shared__ _Float16 un[12544];   // union: W (9216) | out staging 128 x 98
    __shared__ float bias_s[96];
    int t = threadIdx.x, bid = blockIdx.x;
    { int xcd = bid & 7; bid = xcd * 125 + (bid >> 3); }   // chain conv3's XCD map
    int b = bid / 500, s0 = (bid % 500) * 128;
    for (int i = t; i < 1152; i += 256) ((uint4*)un)[i] = ((const uint4*)w)[i];
    if (t < 96) bias_s[t] = bias[t];
    __syncthreads();

    int ws = t >> 6, lane = t & 63;
    int n = lane & 31, kg = lane >> 5;
    int p = ws * 32 + n;
    const uint4* brow = (const uint4*)(in + ((size_t)(b * 64000 + s0 + p)) * 96);
    uint4 bf[6];
#pragma unroll
    for (int kc = 0; kc < 6; kc++) bf[kc] = brow[kc * 2 + kg];

    floatx16 acc[3];
#pragma unroll
    for (int mt = 0; mt < 3; mt++)
#pragma unroll
        for (int r = 0; r < 16; r++) acc[mt][r] = 0.f;
#pragma unroll
    for (int kc = 0; kc < 6; kc++) {
        half8 bfh = __builtin_bit_cast(half8, bf[kc]);
#pragma unroll
        for (int mt = 0; mt < 3; mt++) {
            uint4 au = *(const uint4*)&un[(mt * 32 + n) * 96 + kc * 16 + kg * 8];
            acc[mt] = __builtin_amdgcn_mfma_f32_32x32x16_f16(__builtin_bit_cast(half8, au), bfh, acc[mt], 0, 0, 0);
        }
    }
    __syncthreads();   // done reading W; un becomes output staging

#pragma unroll
    for (int mt = 0; mt < 3; mt++)
#pragma unroll
        for (int r = 0; r < 16; r++) {
            int m = mt * 32 + (r & 3) + 8 * (r >> 2) + 4 * kg;
            int sl = ws * 32 + n;
            float v = acc[mt][r] + bias_s[m];
            if (MODE == 1) {
                v = 1.f / (1.f + __expf(-v));
                v *= xg[((size_t)(b * 96 + m)) * 64000 + s0 + sl];
            }
            un[sl * 98 + m] = (_Float16)v;
        }
    __syncthreads();

    unsigned int* dst = (unsigned int*)(outp + ((size_t)(b * 64000 + s0)) * 96);
    for (int i = t; i < 6144; i += 256) {
        int row = i / 48, sg = i % 48;
        dst[i] = *(const unsigned int*)&un[row * 98 + sg * 2];
    }
}

// ---------------- qkv GEMM (ONCE): qA[b][s][288] f16, natural s-order ----------------
__global__ __launch_bounds__(256) void k_qkv(const _Float16* __restrict__ xt,
                                             const _Float16* __restrict__ wq,  // [288][96]
                                             const float* __restrict__ qb,
                                             _Float16* __restrict__ qA) {
    __shared__ _Float16 smem[27648];   // union: A (288x96) then epi (64 x 296)
    __shared__ float bias_s[288];
    int t = threadIdx.x;
    int bid = blockIdx.x;
    { int xcd = bid & 7; bid = xcd * 125 + (bid >> 3); }   // chain conv3's XCD map
    int b = bid / 500;
    int s0 = (bid % 500) * 128;

    for (int i = t; i < 3456; i += 256) ((uint4*)smem)[i] = ((const uint4*)wq)[i];
    for (int i = t; i < 288; i += 256) bias_s[i] = qb[i];
    __syncthreads();

    int ws = t >> 6, lane = t & 63;
    int n = lane & 31, kg = lane >> 5;
    int p = ws * 32 + n;

    const uint4* brow = (const uint4*)(xt + ((size_t)(b * 64000 + s0 + p)) * 96);
    uint4 bf[6];
#pragma unroll
    for (int kc = 0; kc < 6; kc++) bf[kc] = brow[kc * 2 + kg];

    floatx16 acc[9];
#pragma unroll
    for (int mt = 0; mt < 9; mt++)
#pragma unroll
        for (int r = 0; r < 16; r++) acc[mt][r] = 0.f;

#pragma unroll
    for (int kc = 0; kc < 6; kc++) {
        half8 bfh = __builtin_bit_cast(half8, bf[kc]);
#pragma unroll
        for (int mt = 0; mt < 9; mt++) {
            uint4 au = *(const uint4*)&smem[(mt * 32 + n) * 96 + kc * 16 + kg * 8];
            acc[mt] = __builtin_amdgcn_mfma_f32_32x32x16_f16(__builtin_bit_cast(half8, au), bfh, acc[mt], 0, 0, 0);
        }
    }

    const float scale = 0.20412414523193154f;
    for (int q = 0; q < 2; q++) {
        __syncthreads();
        if ((ws >> 1) == q) {
            int pl = (ws & 1) * 32 + n;
#pragma unroll
            for (int mt = 0; mt < 9; mt++)
#pragma unroll
                for (int g = 0; g < 4; g++) {
                    int m0 = mt * 32 + g * 8 + kg * 4;
                    _Float16 tm[4];
#pragma unroll
                    for (int j = 0; j < 4; j++) {
                        float v = acc[mt][g * 4 + j] + bias_s[m0 + j];
                        if (m0 + j < 96) v *= scale;
                        tm[j] = (_Float16)v;
                    }
                    *(uint2*)&smem[pl * 296 + m0] = *(uint2*)tm;
                }
        }
        __syncthreads();
        for (int idx = t; idx < 2304; idx += 256) {
            int pl = idx / 36, seg = idx % 36;
            int s = s0 + q * 64 + pl;
            uint4 v = *(const uint4*)&smem[pl * 296 + seg * 8];
            *(uint4*)&qA[((size_t)(b * 64000 + s)) * 288 + seg * 8] = v;
        }
    }
}

// ---------------- fused axial attention: softmax + PV, sum into osum[b][s][96] ----------------
// block=320: 2 lines x (4 heads x 40 queries), one query/thread.
template <int AXIS, bool ACC>
__global__ __launch_bounds__(320, 3) void k_attn(const _Float16* __restrict__ qA,
                                                 _Float16* __restrict__ osum) {
    __shared__ _Float16 kk[8352];     // k: [line][key][96]; then out staging [line][l][104]
    __shared__ _Float16 vT[7744];     // plane lh=line*4+head, stride 968: [hd][40 keys]
    int t = threadIdx.x;
    int bid = blockIdx.x;
    bid = (bid & 7) * 200 + (bid >> 3);   // bijective XCD chunking (1600%8==0)
    int b = bid / 800;
    int r0 = (bid % 800) * 2;

    auto smap = [&](int r, int l) -> int {
        if (AXIS == 0) return l * 1600 + r;
        else if (AXIS == 1) { int d = r / 40, w = r % 40; return d * 1600 + l * 40 + w; }
        else return r * 40 + l;
    };
    const uint4* src = (const uint4*)qA;
    for (int i = t; i < 960; i += 320) {
        int line = i / 480, key = (i % 480) / 12, seg = i % 12;
        int row = b * 64000 + smap(r0 + line, key);
        ((uint4*)kk)[i] = src[(size_t)row * 36 + 12 + seg];
    }
    for (int i = t; i < 960; i += 320) {
        int line = i / 480, key = (i % 480) / 12, seg = i % 12;
        int row = b * 64000 + smap(r0 + line, key);
        uint4 v = src[(size_t)row * 36 + 24 + seg];
        _Float16 tmp[8];
        *(uint4*)tmp = v;
#pragma unroll
        for (int e = 0; e < 8; e++) {
            int hdg = seg * 8 + e;
            vT[(line * 4 + hdg / 24) * 968 + (hdg % 24) * 40 + key] = tmp[e];
        }
    }

    int line = t / 160, head = (t % 160) / 40, ql = t % 40;
    int rr = r0 + line;
    unsigned int qu[12];
    {
        const uint4* qp = (const uint4*)(qA + ((size_t)(b * 64000 + smap(rr, ql))) * 288 + head * 24);
#pragma unroll
        for (int j = 0; j < 3; j++) *(uint4*)&qu[j * 4] = qp[j];
    }
    __syncthreads();

    float s[40];
    const uint4* kbase = (const uint4*)kk + line * 480 + head * 3;
#pragma unroll 4
    for (int key = 0; key < 40; key++) {
        unsigned int kku[12];
#pragma unroll
        for (int j = 0; j < 3; j++) *(uint4*)&kku[j * 4] = kbase[key * 12 + j];
        float a = 0.f;
#pragma unroll
        for (int i = 0; i < 12; i++) a = fdot2(kku[i], qu[i], a);
        s[key] = a;
    }

    float mx = -1e30f;
#pragma unroll
    for (int i = 0; i < 40; i++) mx = fmaxf(mx, s[i]);
    float sum = 0.f;
#pragma unroll
    for (int i = 0; i < 40; i++) { s[i] = __expf(s[i] - mx); sum += s[i]; }
    float inv = 1.f / sum;

    unsigned int pw[20];
#pragma unroll
    for (int i = 0; i < 20; i++) {
        half2 a = { (_Float16)(s[2 * i] * inv), (_Float16)(s[2 * i + 1] * inv) };
        pw[i] = __builtin_bit_cast(unsigned int, a);
    }

    __syncthreads();   // kk becomes output staging

    float o[24];
    const uint4* vbase = (const uint4*)vT + (line * 4 + head) * 121;
#pragma unroll 2
    for (int hd = 0; hd < 24; hd++) {
        unsigned int vv[20];
#pragma unroll
        for (int j = 0; j < 5; j++) *(uint4*)&vv[j * 4] = vbase[hd * 5 + j];
        float a = 0.f;
#pragma unroll
        for (int i = 0; i < 20; i++) a = fdot2(vv[i], pw[i], a);
        o[hd] = a;
    }

    {
        _Float16 tm[24];
#pragma unroll
        for (int j = 0; j < 24; j++) tm[j] = (_Float16)o[j];
        _Float16* dA = &kk[(line * 40 + ql) * 104 + head * 24];
#pragma unroll
        for (int j = 0; j < 3; j++) ((uint4*)dA)[j] = ((uint4*)tm)[j];
    }
    __syncthreads();

    // flush 80 rows x 96 f16 to osum[smap(r,l)] (192B rows; contiguous for AXIS 2)
    uint4* dst = (uint4*)osum;
    for (int i = t; i < 960; i += 320) {
        int row = i / 12, seg = i % 12;
        int s2 = smap(r0 + row / 40, row % 40);
        size_t di = ((size_t)(b * 64000 + s2)) * 12 + seg;
        uint4 v = *(const uint4*)&kk[row * 104 + seg * 8];
        if (ACC) {
            half8 a = __builtin_bit_cast(half8, dst[di]);
            half8 c = __builtin_bit_cast(half8, v);
            dst[di] = __builtin_bit_cast(uint4, a + c);
        } else {
            dst[di] = v;
        }
    }
}

// ---------------- proj GEMM: out[b][c][s] = proj_w @ osum[b][s][96] + pb ----------------
__global__ __launch_bounds__(256) void k_proj(const _Float16* __restrict__ osum,
                                              const _Float16* __restrict__ wp,  // [96][96]
                                              const float* __restrict__ pb,
                                              float* __restrict__ out) {
    __shared__ _Float16 A[9216];
    __shared__ float bias_s[96];
    int t = threadIdx.x;
    int bid = blockIdx.x;
    int b = bid / 500;
    int s0 = (bid % 500) * 128;
    for (int i = t; i < 1152; i += 256) ((uint4*)A)[i] = ((const uint4*)wp)[i];
    if (t < 96) bias_s[t] = pb[t];
    __syncthreads();

    int ws = t >> 6, lane = t & 63;
    int n = lane & 31, kg = lane >> 5;
    int s = s0 + ws * 32 + n;

    const uint4* brow = (const uint4*)(osum + ((size_t)(b * 64000 + s0 + ws * 32 + n)) * 96);
    uint4 bf[6];
#pragma unroll
    for (int kc = 0; kc < 6; kc++) bf[kc] = brow[kc * 2 + kg];

    floatx16 acc[3];
#pragma unroll
    for (int mt = 0; mt < 3; mt++)
#pragma unroll
        for (int r = 0; r < 16; r++) acc[mt][r] = 0.f;

#pragma unroll
    for (int kc = 0; kc < 6; kc++) {
        half8 bfh = __builtin_bit_cast(half8, bf[kc]);
#pragma unroll
        for (int mt = 0; mt < 3; mt++) {
            uint4 au = *(const uint4*)&A[(mt * 32 + n) * 96 + kc * 16 + kg * 8];
            acc[mt] = __builtin_amdgcn_mfma_f32_32x32x16_f16(__builtin_bit_cast(half8, au), bfh, acc[mt], 0, 0, 0);
        }
    }

#pragma unroll
    for (int mt = 0; mt < 3; mt++)
#pragma unroll
        for (int r = 0; r < 16; r++) {
            int m = mt * 32 + (r & 3) + 8 * (r >> 2) + 4 * kg;
            out[((size_t)(b * 96 + m)) * 64000 + s] = acc[mt][r] + bias_s[m];
        }
}

extern "C" void kernel_launch(void* const* d_in, const int* in_sizes, int n_in,
                              void* d_out, int out_size, void* d_ws, size_t ws_size,
                              hipStream_t stream) {
    const float* x      = (const float*)d_in[0];
    const float* pos    = (const float*)d_in[1];
    const float* qkv_w  = (const float*)d_in[2];
    const float* qkv_b  = (const float*)d_in[3];
    const float* lp1_w  = (const float*)d_in[4];
    const float* lp1_b  = (const float*)d_in[5];
    const float* lp2_w  = (const float*)d_in[6];
    const float* lp2_b  = (const float*)d_in[7];
    const float* mod1_w = (const float*)d_in[8];
    const float* mod1_b = (const float*)d_in[9];
    const float* mod2_w = (const float*)d_in[10];
    const float* mod2_b = (const float*)d_in[11];
    // d_in[12..16]: pa_w, pa_b, R6_d, R6_h, R6_w — provably no-ops (see header)
    const float* proj_w = (const float*)d_in[17];
    const float* proj_b = (const float*)d_in[18];
    float* out = (float*)d_out;
    float* ws = (float*)d_ws;

    // f16 buffers (sizes in f32-float units of ws):
    _Float16* bufA = (_Float16*)ws;                        // 12.288M f16: c3/B0 -> xm
    _Float16* bufB = (_Float16*)(ws + 6144000);            // 12.288M f16: C2/D -> osum
    _Float16* qA   = (_Float16*)(ws + 12288000);           // 36.864M f16
    _Float16* in_t = qA;                                   // pos f16 [s][c], dead before qkv
    _Float16* wf   = (_Float16*)(ws + 30720000);           // 248,832 f16
    _Float16* wq   = (_Float16*)(ws + 30844416);           // 27,648 f16
    _Float16* wpj  = (_Float16*)(ws + 30858240);           // 9,216 f16
    _Float16* wfold= (_Float16*)(ws + 30862848);           // 9,216 f16
    _Float16* wm2  = (_Float16*)(ws + 30867456);           // 9,216 f16
    float* bfold   = ws + 30872064;                        // 96 f32
    float* raw     = ws + 30872160;                        // 768 f32 (raw0 | raw1)
    float* raw0 = raw, *raw1 = raw + 384;

    k_cvt_in<<<2016, 256, 0, stream>>>(pos, in_t);
    k_cvt_w<<<972, 256, 0, stream>>>(lp1_w, wf, raw);     // block 0 zeroes raw
    k_fold<<<36, 256, 0, stream>>>(lp2_w, lp2_b, mod1_w, mod1_b, wfold, bfold);
    k_cvt_f16<<<36, 256, 0, stream>>>(mod2_w, wm2, 9216);
    k_cvt_f16<<<108, 256, 0, stream>>>(qkv_w, wq, 27648);
    k_cvt_f16<<<36, 256, 0, stream>>>(proj_w, wpj, 9216);

    // c3 = conv3(pos)  [f16, [b][s][96]]
    k_conv3_v6<<<500, 256, 0, stream>>>(in_t, wf, lp1_b, bufA);
    // B0 = gelu(IN(c3)) in-place (finalize fused into ng16)
    k_stats_sc<<<100, 192, 0, stream>>>(bufA, raw0);
    k_ng16<<<1500, 256, 0, stream>>>(bufA, raw0);
    // C2 = W' @ B0 + b'   (folded lp2 -> mod1)
    k_gemm96<0><<<1000, 256, 0, stream>>>(bufA, wfold, bfold, nullptr, bufB);
    // D = gelu(IN(C2)) in-place
    k_stats_sc<<<100, 192, 0, stream>>>(bufB, raw1);
    k_ng16<<<1500, 256, 0, stream>>>(bufB, raw1);
    // xm = x * sigmoid(mod2 @ D + b)   [f16 [b][s][96], into bufA (B0 dead)]
    k_gemm96<1><<<1000, 256, 0, stream>>>(bufB, wm2, mod2_b, x, bufA);

    // qkv ONCE (s-order); qA overwrites in_t (dead)
    k_qkv<<<1000, 256, 0, stream>>>(bufA, wq, qkv_b, qA);
    // attention: axis 2 writes osum (contiguous), axes 0/1 accumulate (192B-row RMW)
    k_attn<2, false><<<1600, 320, 0, stream>>>(qA, bufB);
    k_attn<0, true ><<<1600, 320, 0, stream>>>(qA, bufB);
    k_attn<1, true ><<<1600, 320, 0, stream>>>(qA, bufB);

    // out = proj(osum)
    k_proj<<<1000, 256, 0, stream>>>(bufB, wpj, proj_b, out);
}

// Round 7
// 655.722 us; speedup vs baseline: 1.0971x; 1.0971x over previous
//
#include <hip/hip_runtime.h>

// Problem constants: B=2, C=96, D=H=W=40, S=64000, NH=4, HD=24, L=40
// Exact simplifications vs reference:
//  - pos_attn branch dropped (softmax row-shift invariance)
//  - R6 rotations dropped (R orthogonal; (Rq).(Rk) = q.k; v unrotated)
//  - mod1@ (lp2@B + b2) + b1 folded to W'@B + b'  (W' = mod1@lp2, exact)
// History: r7 XCD swizzle (conv3 131->120, FETCH 62->16.5MB). r8-r10 conv3
// rewrites all lost. r12(v6) A-dbuf-via-registers SPILLED (WRITE 257MB =
// rA[5] held across MFMA loop -> scratch); its launch fusions were good
// (rest 538us, best). r13(v7): same A-in-LDS idea, spill-proof:
// __builtin_amdgcn_global_load_lds(16B) stages A HBM/L2->LDS directly (no
// VGPR path). Linear LDS dest (gll constraint) + per-lane SOURCE permutation
// realizes fragment-major layout [j*2+kg][row][16B]; ds_read_b128 A-reads are
// 512B-contiguous (conflict-free). Double-buffered, 1 barrier/tap. TA line
// model: A-stream 2600 -> 288 lines/tap/block; conv3 predicted 60-80us.

typedef __attribute__((ext_vector_type(8))) _Float16 half8;
typedef __attribute__((ext_vector_type(2))) _Float16 half2;
typedef __attribute__((ext_vector_type(16))) float floatx16;

static __device__ __forceinline__ half2 h2(unsigned int u) {
    return __builtin_bit_cast(half2, u);
}
static __device__ __forceinline__ float fdot2(unsigned int a, unsigned int b, float c) {
    return __builtin_amdgcn_fdot2(h2(a), h2(b), c, false);
}

typedef __attribute__((address_space(1))) const void gas_t;
typedef __attribute__((address_space(3))) void las_t;
static __device__ __forceinline__ void gll16(const void* g, void* l) {
    __builtin_amdgcn_global_load_lds((gas_t*)g, (las_t*)l, 16, 0, 0);
}

// ---------------- prep: pos fp32 [b][c][s] -> f16 [b][s][c], XCD-aligned ----------------
__global__ __launch_bounds__(256) void k_cvt_in(const float* __restrict__ pos,
                                                _Float16* __restrict__ in_t) {
    __shared__ _Float16 lds[64][97];
    int bid = blockIdx.x;
    int xcd = bid & 7, k = bid >> 3;      // k 0..251
    int L;
    if (xcd < 4) L = xcd * 63 + (k >> 2);
    else { if (k >= 248) return; L = 252 + (xcd - 4) * 62 + (k >> 2); }
    int q = k & 3;
    int b = L / 250;
    int s0 = (L % 250) * 256 + q * 64;
    int t = threadIdx.x;
    for (int i = t; i < 6144; i += 256) {
        int c = i / 64, sl = i % 64;
        lds[sl][c] = (_Float16)pos[(b * 96 + c) * 64000 + s0 + sl];
    }
    __syncthreads();
    _Float16* outp = in_t + ((size_t)b * 64000 + s0) * 96;
    for (int i = t; i < 6144; i += 256) {
        int sl = i / 96, c = i % 96;
        outp[i] = lds[sl][c];
    }
}

// ---------------- prep: lp1_w [o][c][tap] -> f16 wf [tap][o][c]; block 0 zeroes raw ----------------
__global__ void k_cvt_w(const float* __restrict__ w, _Float16* __restrict__ wf,
                        float* __restrict__ raw) {
    int i = blockIdx.x * 256 + threadIdx.x;
    if (i < 248832) {
        int c = i % 96, m = (i / 96) % 96, tap = i / 9216;
        wf[i] = (_Float16)w[(m * 96 + c) * 27 + tap];
    }
    if (blockIdx.x == 0) {
        for (int u = threadIdx.x; u < 768; u += 256) raw[u] = 0.f;
    }
}

// ---------------- prep: f32 -> f16 straight copy ----------------
__global__ void k_cvt_f16(const float* __restrict__ w, _Float16* __restrict__ o, int n) {
    int i = blockIdx.x * 256 + threadIdx.x;
    if (i < n) o[i] = (_Float16)w[i];
}

// ---------------- prep: W' = mod1_w @ lp2_w (f16), b' = mod1_w @ lp2_b + mod1_b ----------------
__global__ __launch_bounds__(256) void k_fold(const float* __restrict__ lp2_w,
                                              const float* __restrict__ lp2_b,
                                              const float* __restrict__ mod1_w,
                                              const float* __restrict__ mod1_b,
                                              _Float16* __restrict__ wfold,
                                              float* __restrict__ bfold) {
    int i = blockIdx.x * 256 + threadIdx.x;   // grid 36 -> 9216 outputs
    if (i < 9216) {
        int o = i / 96, c = i % 96;
        float a = 0.f;
        for (int k = 0; k < 96; k++) a += mod1_w[o * 96 + k] * lp2_w[k * 96 + c];
        wfold[i] = (_Float16)a;
    }
    if (blockIdx.x == 0 && threadIdx.x < 96) {
        int o = threadIdx.x;
        float a = mod1_b[o];
        for (int k = 0; k < 96; k++) a += mod1_w[o * 96 + k] * lp2_b[k];
        bfold[o] = a;
    }
}

// ---------------- conv 3x3x3 circular: v2 + A staged via global_load_lds ----------------
// A (18KB/tap) staged HBM/L2 -> LDS directly (no VGPRs: spill-proof), double
// buffered, 1 barrier/tap. Linear LDS dest chunks k*1024 + lane*16; per-lane
// SOURCE offset g(u) realizes layout [blk=j*2+kg][row][16B] -> A ds_reads are
// 512B-contiguous (conflict-free). B stays the per-lane L2-local gather.
__global__ __launch_bounds__(256) void k_conv3_v7(const _Float16* __restrict__ in_t,
                                                  const _Float16* __restrict__ wf,  // [tap][m][c]
                                                  const float* __restrict__ bias,
                                                  _Float16* __restrict__ c3) {
    // smem: tbl int[27*256] @0 (27648) | A dbuf 2 x 18432 @27648 | bsh @64512
    __shared__ __align__(16) char smem[64896];
    int* tbl = (int*)smem;
    char* Ab = smem + 27648;
    float* bsh = (float*)(smem + 64512);
    _Float16* st = (_Float16*)smem;       // epilogue staging 50176B (overlays tbl+Ab)

    int t = threadIdx.x;
    int bid = blockIdx.x;
    {   // bijective XCD-chunked remap (nwg=500: q=62, r=4)
        int xcd = bid & 7, idx = bid >> 3;
        bid = (xcd < 4) ? (xcd * 63 + idx) : (252 + (xcd - 4) * 62 + idx);
    }
    int b = bid / 250;
    int s0 = (bid % 250) * 256;

    int wv = t >> 6, lane = t & 63;
    int n31 = lane & 31, kg = lane >> 5;

    // per-thread gll source offsets (fixed across taps): chunk k = wv + 4*i
    // u = k*64+lane; row = u%96; blk = u/96; src = row*192 + (blk>>1)*32 + (blk&1)*16
    int goff[5];
    int nch = (wv < 2) ? 5 : 4;
#pragma unroll
    for (int i = 0; i < 5; i++) {
        int k = wv + 4 * i;
        if (k < 18) {
            int u = k * 64 + lane;
            int row = u % 96, blk = u / 96;
            goff[i] = row * 192 + (blk >> 1) * 32 + (blk & 1) * 16;
        }
    }

    // issue tap-0 A stage into buf 0 (drained by the table barrier below)
    {
        const char* src = (const char*)wf;
#pragma unroll
        for (int i = 0; i < 5; i++) {
            int k = wv + 4 * i;
            if (k < 18) gll16(src + goff[i], Ab + k * 1024);
        }
    }

    for (int u = t; u < 27 * 256; u += 256) {
        int tap = u >> 8, nl = u & 255;
        int kd = tap / 9, kh = (tap / 3) % 3, kw = tap % 3;
        int s = s0 + nl;
        int d = s / 1600, r = s - d * 1600;
        int h = r / 40, w = r - h * 40;
        int ds = d + kd - 1; if (ds < 0) ds += 40; else if (ds >= 40) ds -= 40;
        int hs = h + kh - 1; if (hs < 0) hs += 40; else if (hs >= 40) hs -= 40;
        int wv2 = w + kw - 1; if (wv2 < 0) wv2 += 40; else if (wv2 >= 40) wv2 -= 40;
        tbl[u] = ((ds * 1600 + hs * 40 + wv2) * 96) * 2;   // byte offset in batch slab
    }
    if (t < 96) bsh[t] = bias[t];
    __syncthreads();   // tbl ready AND tap-0 A landed (barrier drains vmcnt)

    const char* inb = (const char*)(in_t + (size_t)b * 64000 * 96) + kg * 16;

    floatx16 acc[3][2];
#pragma unroll
    for (int mt = 0; mt < 3; mt++)
#pragma unroll
        for (int nt = 0; nt < 2; nt++)
#pragma unroll
            for (int r = 0; r < 16; r++) acc[mt][nt][r] = 0.f;

    for (int tap = 0; tap < 27; tap++) {
        int cur = tap & 1;
        if (tap < 26) {   // prefetch next tap's A straight into the other buffer
            const char* src = (const char*)wf + (tap + 1) * 18432;
            char* dstb = Ab + (cur ^ 1) * 18432;
#pragma unroll
            for (int i = 0; i < 5; i++) {
                int k = wv + 4 * i;
                if (k < 18) gll16(src + goff[i], dstb + k * 1024);
            }
        }
        int ta0 = tbl[tap * 256 + wv * 64 + n31];
        int ta1 = tbl[tap * 256 + wv * 64 + 32 + n31];
        const char* pb0 = inb + ta0;
        const char* pb1 = inb + ta1;
        const char* Ac = Ab + cur * 18432 + kg * 1536 + n31 * 16;
#pragma unroll
        for (int j = 0; j < 6; j++) {
            half8 b0 = *(const half8*)(pb0 + j * 32);
            half8 b1 = *(const half8*)(pb1 + j * 32);
            const char* Aj = Ac + j * 3072;
            half8 a0 = *(const half8*)(Aj);
            half8 a1 = *(const half8*)(Aj + 512);
            half8 a2 = *(const half8*)(Aj + 1024);
            acc[0][0] = __builtin_amdgcn_mfma_f32_32x32x16_f16(a0, b0, acc[0][0], 0, 0, 0);
            acc[0][1] = __builtin_amdgcn_mfma_f32_32x32x16_f16(a0, b1, acc[0][1], 0, 0, 0);
            acc[1][0] = __builtin_amdgcn_mfma_f32_32x32x16_f16(a1, b0, acc[1][0], 0, 0, 0);
            acc[1][1] = __builtin_amdgcn_mfma_f32_32x32x16_f16(a1, b1, acc[1][1], 0, 0, 0);
            acc[2][0] = __builtin_amdgcn_mfma_f32_32x32x16_f16(a2, b0, acc[2][0], 0, 0, 0);
            acc[2][1] = __builtin_amdgcn_mfma_f32_32x32x16_f16(a2, b1, acc[2][1], 0, 0, 0);
        }
        __syncthreads();   // next-tap A landed; buffers swap
    }

    // epilogue: padded transpose (st overlays tbl/Ab; safe after final barrier)
#pragma unroll
    for (int mt = 0; mt < 3; mt++)
#pragma unroll
        for (int nt = 0; nt < 2; nt++)
#pragma unroll
            for (int r = 0; r < 16; r++) {
                int m = mt * 32 + (r & 3) + 8 * (r >> 2) + 4 * kg;
                int sl = wv * 64 + nt * 32 + n31;
                st[sl * 98 + m] = (_Float16)(acc[mt][nt][r] + bsh[m]);
            }
    __syncthreads();

    unsigned int* dst = (unsigned int*)(c3 + ((size_t)(b * 64000 + s0)) * 96);
    for (int i = t; i < 12288; i += 256) {
        int row = i / 48, sg = i % 48;
        dst[i] = *(const unsigned int*)&st[row * 98 + sg * 2];
    }
}

// ---------------- per-(b,c) stats over f16 [b][s][96]: atomic partial sums ----------------
__global__ __launch_bounds__(192) void k_stats_sc(const _Float16* __restrict__ in,
                                                  float* __restrict__ raw) {   // [192][2]
    __shared__ float red_s[16][96], red_q[16][96];
    int bid = blockIdx.x;            // 100 blocks: b = bid/50, chunk of 1280 s
    int b = bid / 50, ch = bid % 50;
    int t = threadIdx.x;
    int sp = t / 12, cs = t % 12;
    const uint4* base = (const uint4*)(in + ((size_t)(b * 64000 + ch * 1280)) * 96);
    float s8[8], q8[8];
#pragma unroll
    for (int e = 0; e < 8; e++) { s8[e] = 0.f; q8[e] = 0.f; }
    for (int i = 0; i < 80; i++) {
        uint4 v = base[(sp + i * 16) * 12 + cs];
        half8 h = __builtin_bit_cast(half8, v);
#pragma unroll
        for (int e = 0; e < 8; e++) { float f = (float)h[e]; s8[e] += f; q8[e] += f * f; }
    }
#pragma unroll
    for (int e = 0; e < 8; e++) { red_s[sp][cs * 8 + e] = s8[e]; red_q[sp][cs * 8 + e] = q8[e]; }
    __syncthreads();
    if (t < 96) {
        float S = 0.f, Q = 0.f;
        for (int k = 0; k < 16; k++) { S += red_s[k][t]; Q += red_q[k][t]; }
        atomicAdd(&raw[(b * 96 + t) * 2], S);
        atomicAdd(&raw[(b * 96 + t) * 2 + 1], Q);
    }
}

// ---------------- norm + exact gelu on f16 [b][s][96], in-place; finalize fused ----------------
__global__ __launch_bounds__(256) void k_ng16(_Float16* __restrict__ x, const float* __restrict__ raw) {
    __shared__ float2 sfs[192];
    int t = threadIdx.x, bid = blockIdx.x;
    if (t < 192) {
        float S = raw[t * 2], Q = raw[t * 2 + 1];
        float mu = S * (1.f / 64000.f);
        float var = Q * (1.f / 64000.f) - mu * mu;
        sfs[t] = make_float2(mu, rsqrtf(var + 1e-5f));
    }
    __syncthreads();
    uint4* p = (uint4*)x;
#pragma unroll
    for (int k = 0; k < 4; k++) {
        int i = bid * 1024 + k * 256 + t;      // uint4 index, 1,536,000 total
        int e0 = i * 8;
        int b = e0 / 6144000;
        int c0 = e0 % 96;
        const float2* sp = &sfs[b * 96 + c0];
        uint4 v = p[i];
        half8 h = __builtin_bit_cast(half8, v);
        _Float16 o[8];
#pragma unroll
        for (int e = 0; e < 8; e++) {
            float2 st = sp[e];
            float u = ((float)h[e] - st.x) * st.y;
            o[e] = (_Float16)(0.5f * u * (1.f + erff(u * 0.70710678118654752f)));
        }
        p[i] = *(uint4*)o;
    }
}

// ---------------- 96x96 f16 MFMA GEMM on [b][s][96]; MODE 1: sigmoid * x epilogue ----------------
template <int MODE>
__global__ __launch_bounds__(256) void k_gemm96(const _Float16* __restrict__ in,
                                                const _Float16* __restrict__ w,   // [96][96]
                                                const float* __restrict__ bias,
                                                const float* __restrict__ xg,     // [b][c][s] f32 (MODE 1)
                                                _Float16* __restrict__ outp) {
    __shared__ _Float16 un[12544];   // union: W (9216) | out staging 128 x 98
    __shared__ float bias_s[96];
    int t = threadIdx.x, bid = blockIdx.x;
    { int xcd = bid & 7; bid = xcd * 125 + (bid >> 3); }   // chain conv3's XCD map
    int b = bid / 500, s0 = (bid % 500) * 128;
    for (int i = t; i < 1152; i += 256) ((uint4*)un)[i] = ((const uint4*)w)[i];
    if (t < 96) bias_s[t] = bias[t];
    __syncthreads();

    int ws = t >> 6, lane = t & 63;
    int n = lane & 31, kg = lane >> 5;
    int p = ws * 32 + n;
    const uint4* brow = (const uint4*)(in + ((size_t)(b * 64000 + s0 + p)) * 96);
    uint4 bf[6];
#pragma unroll
    for (int kc = 0; kc < 6; kc++) bf[kc] = brow[kc * 2 + kg];

    floatx16 acc[3];
#pragma unroll
    for (int mt = 0; mt < 3; mt++)
#pragma unroll
        for (int r = 0; r < 16; r++) acc[mt][r] = 0.f;
#pragma unroll
    for (int kc = 0; kc < 6; kc++) {
        half8 bfh = __builtin_bit_cast(half8, bf[kc]);
#pragma unroll
        for (int mt = 0; mt < 3; mt++) {
            uint4 au = *(const uint4*)&un[(mt * 32 + n) * 96 + kc * 16 + kg * 8];
            acc[mt] = __builtin_amdgcn_mfma_f32_32x32x16_f16(__builtin_bit_cast(half8, au), bfh, acc[mt], 0, 0, 0);
        }
    }
    __syncthreads();   // done reading W; un becomes output staging

#pragma unroll
    for (int mt = 0; mt < 3; mt++)
#pragma unroll
        for (int r = 0; r < 16; r++) {
            int m = mt * 32 + (r & 3) + 8 * (r >> 2) + 4 * kg;
            int sl = ws * 32 + n;
            float v = acc[mt][r] + bias_s[m];
            if (MODE == 1) {
                v = 1.f / (1.f + __expf(-v));
                v *= xg[((size_t)(b * 96 + m)) * 64000 + s0 + sl];
            }
            un[sl * 98 + m] = (_Float16)v;
        }
    __syncthreads();

    unsigned int* dst = (unsigned int*)(outp + ((size_t)(b * 64000 + s0)) * 96);
    for (int i = t; i < 6144; i += 256) {
        int row = i / 48, sg = i % 48;
        dst[i] = *(const unsigned int*)&un[row * 98 + sg * 2];
    }
}

// ---------------- qkv GEMM (ONCE): qA[b][s][288] f16, natural s-order ----------------
__global__ __launch_bounds__(256) void k_qkv(const _Float16* __restrict__ xt,
                                             const _Float16* __restrict__ wq,  // [288][96]
                                             const float* __restrict__ qb,
                                             _Float16* __restrict__ qA) {
    __shared__ _Float16 smem[27648];   // union: A (288x96) then epi (64 x 296)
    __shared__ float bias_s[288];
    int t = threadIdx.x;
    int bid = blockIdx.x;
    { int xcd = bid & 7; bid = xcd * 125 + (bid >> 3); }   // chain conv3's XCD map
    int b = bid / 500;
    int s0 = (bid % 500) * 128;

    for (int i = t; i < 3456; i += 256) ((uint4*)smem)[i] = ((const uint4*)wq)[i];
    for (int i = t; i < 288; i += 256) bias_s[i] = qb[i];
    __syncthreads();

    int ws = t >> 6, lane = t & 63;
    int n = lane & 31, kg = lane >> 5;
    int p = ws * 32 + n;

    const uint4* brow = (const uint4*)(xt + ((size_t)(b * 64000 + s0 + p)) * 96);
    uint4 bf[6];
#pragma unroll
    for (int kc = 0; kc < 6; kc++) bf[kc] = brow[kc * 2 + kg];

    floatx16 acc[9];
#pragma unroll
    for (int mt = 0; mt < 9; mt++)
#pragma unroll
        for (int r = 0; r < 16; r++) acc[mt][r] = 0.f;

#pragma unroll
    for (int kc = 0; kc < 6; kc++) {
        half8 bfh = __builtin_bit_cast(half8, bf[kc]);
#pragma unroll
        for (int mt = 0; mt < 9; mt++) {
            uint4 au = *(const uint4*)&smem[(mt * 32 + n) * 96 + kc * 16 + kg * 8];
            acc[mt] = __builtin_amdgcn_mfma_f32_32x32x16_f16(__builtin_bit_cast(half8, au), bfh, acc[mt], 0, 0, 0);
        }
    }

    const float scale = 0.20412414523193154f;
    for (int q = 0; q < 2; q++) {
        __syncthreads();
        if ((ws >> 1) == q) {
            int pl = (ws & 1) * 32 + n;
#pragma unroll
            for (int mt = 0; mt < 9; mt++)
#pragma unroll
                for (int g = 0; g < 4; g++) {
                    int m0 = mt * 32 + g * 8 + kg * 4;
                    _Float16 tm[4];
#pragma unroll
                    for (int j = 0; j < 4; j++) {
                        float v = acc[mt][g * 4 + j] + bias_s[m0 + j];
                        if (m0 + j < 96) v *= scale;
                        tm[j] = (_Float16)v;
                    }
                    *(uint2*)&smem[pl * 296 + m0] = *(uint2*)tm;
                }
        }
        __syncthreads();
        for (int idx = t; idx < 2304; idx += 256) {
            int pl = idx / 36, seg = idx % 36;
            int s = s0 + q * 64 + pl;
            uint4 v = *(const uint4*)&smem[pl * 296 + seg * 8];
            *(uint4*)&qA[((size_t)(b * 64000 + s)) * 288 + seg * 8] = v;
        }
    }
}

// ---------------- fused axial attention: softmax + PV, sum into osum[b][s][96] ----------------
// block=320: 2 lines x (4 heads x 40 queries), one query/thread.
template <int AXIS, bool ACC>
__global__ __launch_bounds__(320, 3) void k_attn(const _Float16* __restrict__ qA,
                                                 _Float16* __restrict__ osum) {
    __shared__ _Float16 kk[8352];     // k: [line][key][96]; then out staging [line][l][104]
    __shared__ _Float16 vT[7744];     // plane lh=line*4+head, stride 968: [hd][40 keys]
    int t = threadIdx.x;
    int bid = blockIdx.x;
    bid = (bid & 7) * 200 + (bid >> 3);   // bijective XCD chunking (1600%8==0)
    int b = bid / 800;
    int r0 = (bid % 800) * 2;

    auto smap = [&](int r, int l) -> int {
        if (AXIS == 0) return l * 1600 + r;
        else if (AXIS == 1) { int d = r / 40, w = r % 40; return d * 1600 + l * 40 + w; }
        else return r * 40 + l;
    };
    const uint4* src = (const uint4*)qA;
    for (int i = t; i < 960; i += 320) {
        int line = i / 480, key = (i % 480) / 12, seg = i % 12;
        int row = b * 64000 + smap(r0 + line, key);
        ((uint4*)kk)[i] = src[(size_t)row * 36 + 12 + seg];
    }
    for (int i = t; i < 960; i += 320) {
        int line = i / 480, key = (i % 480) / 12, seg = i % 12;
        int row = b * 64000 + smap(r0 + line, key);
        uint4 v = src[(size_t)row * 36 + 24 + seg];
        _Float16 tmp[8];
        *(uint4*)tmp = v;
#pragma unroll
        for (int e = 0; e < 8; e++) {
            int hdg = seg * 8 + e;
            vT[(line * 4 + hdg / 24) * 968 + (hdg % 24) * 40 + key] = tmp[e];
        }
    }

    int line = t / 160, head = (t % 160) / 40, ql = t % 40;
    int rr = r0 + line;
    unsigned int qu[12];
    {
        const uint4* qp = (const uint4*)(qA + ((size_t)(b * 64000 + smap(rr, ql))) * 288 + head * 24);
#pragma unroll
        for (int j = 0; j < 3; j++) *(uint4*)&qu[j * 4] = qp[j];
    }
    __syncthreads();

    float s[40];
    const uint4* kbase = (const uint4*)kk + line * 480 + head * 3;
#pragma unroll 4
    for (int key = 0; key < 40; key++) {
        unsigned int kku[12];
#pragma unroll
        for (int j = 0; j < 3; j++) *(uint4*)&kku[j * 4] = kbase[key * 12 + j];
        float a = 0.f;
#pragma unroll
        for (int i = 0; i < 12; i++) a = fdot2(kku[i], qu[i], a);
        s[key] = a;
    }

    float mx = -1e30f;
#pragma unroll
    for (int i = 0; i < 40; i++) mx = fmaxf(mx, s[i]);
    float sum = 0.f;
#pragma unroll
    for (int i = 0; i < 40; i++) { s[i] = __expf(s[i] - mx); sum += s[i]; }
    float inv = 1.f / sum;

    unsigned int pw[20];
#pragma unroll
    for (int i = 0; i < 20; i++) {
        half2 a = { (_Float16)(s[2 * i] * inv), (_Float16)(s[2 * i + 1] * inv) };
        pw[i] = __builtin_bit_cast(unsigned int, a);
    }

    __syncthreads();   // kk becomes output staging

    float o[24];
    const uint4* vbase = (const uint4*)vT + (line * 4 + head) * 121;
#pragma unroll 2
    for (int hd = 0; hd < 24; hd++) {
        unsigned int vv[20];
#pragma unroll
        for (int j = 0; j < 5; j++) *(uint4*)&vv[j * 4] = vbase[hd * 5 + j];
        float a = 0.f;
#pragma unroll
        for (int i = 0; i < 20; i++) a = fdot2(vv[i], pw[i], a);
        o[hd] = a;
    }

    {
        _Float16 tm[24];
#pragma unroll
        for (int j = 0; j < 24; j++) tm[j] = (_Float16)o[j];
        _Float16* dA = &kk[(line * 40 + ql) * 104 + head * 24];
#pragma unroll
        for (int j = 0; j < 3; j++) ((uint4*)dA)[j] = ((uint4*)tm)[j];
    }
    __syncthreads();

    // flush 80 rows x 96 f16 to osum[smap(r,l)] (192B rows; contiguous for AXIS 2)
    uint4* dst = (uint4*)osum;
    for (int i = t; i < 960; i += 320) {
        int row = i / 12, seg = i % 12;
        int s2 = smap(r0 + row / 40, row % 40);
        size_t di = ((size_t)(b * 64000 + s2)) * 12 + seg;
        uint4 v = *(const uint4*)&kk[row * 104 + seg * 8];
        if (ACC) {
            half8 a = __builtin_bit_cast(half8, dst[di]);
            half8 c = __builtin_bit_cast(half8, v);
            dst[di] = __builtin_bit_cast(uint4, a + c);
        } else {
            dst[di] = v;
        }
    }
}

// ---------------- proj GEMM: out[b][c][s] = proj_w @ osum[b][s][96] + pb ----------------
__global__ __launch_bounds__(256) void k_proj(const _Float16* __restrict__ osum,
                                              const _Float16* __restrict__ wp,  // [96][96]
                                              const float* __restrict__ pb,
                                              float* __restrict__ out) {
    __shared__ _Float16 A[9216];
    __shared__ float bias_s[96];
    int t = threadIdx.x;
    int bid = blockIdx.x;
    int b = bid / 500;
    int s0 = (bid % 500) * 128;
    for (int i = t; i < 1152; i += 256) ((uint4*)A)[i] = ((const uint4*)wp)[i];
    if (t < 96) bias_s[t] = pb[t];
    __syncthreads();

    int ws = t >> 6, lane = t & 63;
    int n = lane & 31, kg = lane >> 5;
    int s = s0 + ws * 32 + n;

    const uint4* brow = (const uint4*)(osum + ((size_t)(b * 64000 + s0 + ws * 32 + n)) * 96);
    uint4 bf[6];
#pragma unroll
    for (int kc = 0; kc < 6; kc++) bf[kc] = brow[kc * 2 + kg];

    floatx16 acc[3];
#pragma unroll
    for (int mt = 0; mt < 3; mt++)
#pragma unroll
        for (int r = 0; r < 16; r++) acc[mt][r] = 0.f;

#pragma unroll
    for (int kc = 0; kc < 6; kc++) {
        half8 bfh = __builtin_bit_cast(half8, bf[kc]);
#pragma unroll
        for (int mt = 0; mt < 3; mt++) {
            uint4 au = *(const uint4*)&A[(mt * 32 + n) * 96 + kc * 16 + kg * 8];
            acc[mt] = __builtin_amdgcn_mfma_f32_32x32x16_f16(__builtin_bit_cast(half8, au), bfh, acc[mt], 0, 0, 0);
        }
    }

#pragma unroll
    for (int mt = 0; mt < 3; mt++)
#pragma unroll
        for (int r = 0; r < 16; r++) {
            int m = mt * 32 + (r & 3) + 8 * (r >> 2) + 4 * kg;
            out[((size_t)(b * 96 + m)) * 64000 + s] = acc[mt][r] + bias_s[m];
        }
}

extern "C" void kernel_launch(void* const* d_in, const int* in_sizes, int n_in,
                              void* d_out, int out_size, void* d_ws, size_t ws_size,
                              hipStream_t stream) {
    const float* x      = (const float*)d_in[0];
    const float* pos    = (const float*)d_in[1];
    const float* qkv_w  = (const float*)d_in[2];
    const float* qkv_b  = (const float*)d_in[3];
    const float* lp1_w  = (const float*)d_in[4];
    const float* lp1_b  = (const float*)d_in[5];
    const float* lp2_w  = (const float*)d_in[6];
    const float* lp2_b  = (const float*)d_in[7];
    const float* mod1_w = (const float*)d_in[8];
    const float* mod1_b = (const float*)d_in[9];
    const float* mod2_w = (const float*)d_in[10];
    const float* mod2_b = (const float*)d_in[11];
    // d_in[12..16]: pa_w, pa_b, R6_d, R6_h, R6_w — provably no-ops (see header)
    const float* proj_w = (const float*)d_in[17];
    const float* proj_b = (const float*)d_in[18];
    float* out = (float*)d_out;
    float* ws = (float*)d_ws;

    // f16 buffers (sizes in f32-float units of ws):
    _Float16* bufA = (_Float16*)ws;                        // 12.288M f16: c3/B0 -> xm
    _Float16* bufB = (_Float16*)(ws + 6144000);            // 12.288M f16: C2/D -> osum
    _Float16* qA   = (_Float16*)(ws + 12288000);           // 36.864M f16
    _Float16* in_t = qA;                                   // pos f16 [s][c], dead before qkv
    _Float16* wf   = (_Float16*)(ws + 30720000);           // 248,832 f16
    _Float16* wq   = (_Float16*)(ws + 30844416);           // 27,648 f16
    _Float16* wpj  = (_Float16*)(ws + 30858240);           // 9,216 f16
    _Float16* wfold= (_Float16*)(ws + 30862848);           // 9,216 f16
    _Float16* wm2  = (_Float16*)(ws + 30867456);           // 9,216 f16
    float* bfold   = ws + 30872064;                        // 96 f32
    float* raw     = ws + 30872160;                        // 768 f32 (raw0 | raw1)
    float* raw0 = raw, *raw1 = raw + 384;

    k_cvt_in<<<2016, 256, 0, stream>>>(pos, in_t);
    k_cvt_w<<<972, 256, 0, stream>>>(lp1_w, wf, raw);     // block 0 zeroes raw
    k_fold<<<36, 256, 0, stream>>>(lp2_w, lp2_b, mod1_w, mod1_b, wfold, bfold);
    k_cvt_f16<<<36, 256, 0, stream>>>(mod2_w, wm2, 9216);
    k_cvt_f16<<<108, 256, 0, stream>>>(qkv_w, wq, 27648);
    k_cvt_f16<<<36, 256, 0, stream>>>(proj_w, wpj, 9216);

    // c3 = conv3(pos)  [f16, [b][s][96]]
    k_conv3_v7<<<500, 256, 0, stream>>>(in_t, wf, lp1_b, bufA);
    // B0 = gelu(IN(c3)) in-place (finalize fused into ng16)
    k_stats_sc<<<100, 192, 0, stream>>>(bufA, raw0);
    k_ng16<<<1500, 256, 0, stream>>>(bufA, raw0);
    // C2 = W' @ B0 + b'   (folded lp2 -> mod1)
    k_gemm96<0><<<1000, 256, 0, stream>>>(bufA, wfold, bfold, nullptr, bufB);
    // D = gelu(IN(C2)) in-place
    k_stats_sc<<<100, 192, 0, stream>>>(bufB, raw1);
    k_ng16<<<1500, 256, 0, stream>>>(bufB, raw1);
    // xm = x * sigmoid(mod2 @ D + b)   [f16 [b][s][96], into bufA (B0 dead)]
    k_gemm96<1><<<1000, 256, 0, stream>>>(bufB, wm2, mod2_b, x, bufA);

    // qkv ONCE (s-order); qA overwrites in_t (dead)
    k_qkv<<<1000, 256, 0, stream>>>(bufA, wq, qkv_b, qA);
    // attention: axis 2 writes osum (contiguous), axes 0/1 accumulate (192B-row RMW)
    k_attn<2, false><<<1600, 320, 0, stream>>>(qA, bufB);
    k_attn<0, true ><<<1600, 320, 0, stream>>>(qA, bufB);
    k_attn<1, true ><<<1600, 320, 0, stream>>>(qA, bufB);

    // out = proj(osum)
    k_proj<<<1000, 256, 0, stream>>>(bufB, wpj, proj_b, out);
}

// Round 10
// 649.617 us; speedup vs baseline: 1.1074x; 1.0094x over previous
//
#include <hip/hip_runtime.h>

// Problem constants: B=2, C=96, D=H=W=40, S=64000, NH=4, HD=24, L=40
// Exact simplifications vs reference:
//  - pos_attn branch dropped (softmax row-shift invariance)
//  - R6 rotations dropped (R orthogonal; (Rq).(Rk) = q.k; v unrotated)
//  - mod1@ (lp2@B + b2) + b1 folded to W'@B + b'  (W' = mod1@lp2, exact)
// History: r7 XCD swizzle (FETCH 62->16.5MB, conv3 131->120). r8-r10 conv3
// rewrites lost. r12 reg-dbuf spilled (WRITE 257MB); launch fusions kept.
// r13(v7) WIN: A staged HBM/L2->LDS via global_load_lds, dbuf, 1 barrier/tap:
// conv3 120->98.2, MfmaUtil 28%. r14/r15(v8) FAILED: compacted tables moved
// bsh to 46080 — INSIDE the epilogue st range [0,50176) — st rows sl>=235
// clobbered bsh while other threads read it -> NaN (and the r14 container
// crash). r16(v8b): identical v8 but bsh relocated to 50176 (after st).
// smem 50560B -> still 3 blocks/CU (12 waves/CU) for latency hiding.

typedef __attribute__((ext_vector_type(8))) _Float16 half8;
typedef __attribute__((ext_vector_type(2))) _Float16 half2;
typedef __attribute__((ext_vector_type(16))) float floatx16;

static __device__ __forceinline__ half2 h2(unsigned int u) {
    return __builtin_bit_cast(half2, u);
}
static __device__ __forceinline__ float fdot2(unsigned int a, unsigned int b, float c) {
    return __builtin_amdgcn_fdot2(h2(a), h2(b), c, false);
}

typedef __attribute__((address_space(1))) const void gas_t;
typedef __attribute__((address_space(3))) void las_t;
static __device__ __forceinline__ void gll16(const void* g, void* l) {
    __builtin_amdgcn_global_load_lds((gas_t*)g, (las_t*)l, 16, 0, 0);
}

// ---------------- prep: pos fp32 [b][c][s] -> f16 [b][s][c], XCD-aligned ----------------
__global__ __launch_bounds__(256) void k_cvt_in(const float* __restrict__ pos,
                                                _Float16* __restrict__ in_t) {
    __shared__ _Float16 lds[64][97];
    int bid = blockIdx.x;
    int xcd = bid & 7, k = bid >> 3;      // k 0..251
    int L;
    if (xcd < 4) L = xcd * 63 + (k >> 2);
    else { if (k >= 248) return; L = 252 + (xcd - 4) * 62 + (k >> 2); }
    int q = k & 3;
    int b = L / 250;
    int s0 = (L % 250) * 256 + q * 64;
    int t = threadIdx.x;
    for (int i = t; i < 6144; i += 256) {
        int c = i / 64, sl = i % 64;
        lds[sl][c] = (_Float16)pos[(b * 96 + c) * 64000 + s0 + sl];
    }
    __syncthreads();
    _Float16* outp = in_t + ((size_t)b * 64000 + s0) * 96;
    for (int i = t; i < 6144; i += 256) {
        int sl = i / 96, c = i % 96;
        outp[i] = lds[sl][c];
    }
}

// ---------------- prep: lp1_w [o][c][tap] -> f16 wf [tap][o][c]; block 0 zeroes raw ----------------
__global__ void k_cvt_w(const float* __restrict__ w, _Float16* __restrict__ wf,
                        float* __restrict__ raw) {
    int i = blockIdx.x * 256 + threadIdx.x;
    if (i < 248832) {
        int c = i % 96, m = (i / 96) % 96, tap = i / 9216;
        wf[i] = (_Float16)w[(m * 96 + c) * 27 + tap];
    }
    if (blockIdx.x == 0) {
        for (int u = threadIdx.x; u < 768; u += 256) raw[u] = 0.f;
    }
}

// ---------------- prep: f32 -> f16 straight copy ----------------
__global__ void k_cvt_f16(const float* __restrict__ w, _Float16* __restrict__ o, int n) {
    int i = blockIdx.x * 256 + threadIdx.x;
    if (i < n) o[i] = (_Float16)w[i];
}

// ---------------- prep: W' = mod1_w @ lp2_w (f16), b' = mod1_w @ lp2_b + mod1_b ----------------
__global__ __launch_bounds__(256) void k_fold(const float* __restrict__ lp2_w,
                                              const float* __restrict__ lp2_b,
                                              const float* __restrict__ mod1_w,
                                              const float* __restrict__ mod1_b,
                                              _Float16* __restrict__ wfold,
                                              float* __restrict__ bfold) {
    int i = blockIdx.x * 256 + threadIdx.x;   // grid 36 -> 9216 outputs
    if (i < 9216) {
        int o = i / 96, c = i % 96;
        float a = 0.f;
        for (int k = 0; k < 96; k++) a += mod1_w[o * 96 + k] * lp2_w[k * 96 + c];
        wfold[i] = (_Float16)a;
    }
    if (blockIdx.x == 0 && threadIdx.x < 96) {
        int o = threadIdx.x;
        float a = mod1_b[o];
        for (int k = 0; k < 96; k++) a += mod1_w[o * 96 + k] * lp2_b[k];
        bfold[o] = a;
    }
}

// ---------------- conv 3x3x3 circular: A via global_load_lds dbuf; compact addr tables ----------------
// v8b: adh[9][256] (9.2KB) + per-lane w-wrap; bsh at 50176 (OUTSIDE the
// epilogue st range — the v8 NaN was st rows >=235 clobbering bsh at 46080).
__global__ __launch_bounds__(256) void k_conv3_v8(const _Float16* __restrict__ in_t,
                                                  const _Float16* __restrict__ wf,  // [tap][m][c]
                                                  const float* __restrict__ bias,
                                                  _Float16* __restrict__ c3) {
    // smem: adh int[9][256] @0 (9216) | A dbuf 2x18432 @9216 (36864, ends 46080)
    //       | bsh float[96] @50176 (384). Epilogue st f16[256*98] @0 (50176).
    __shared__ __align__(16) char smem[50560];
    int* adh = (int*)smem;
    char* Ab = smem + 9216;
    float* bsh = (float*)(smem + 50176);
    _Float16* st = (_Float16*)smem;

    int t = threadIdx.x;
    int bid = blockIdx.x;
    {   // bijective XCD-chunked remap (nwg=500: q=62, r=4)
        int xcd = bid & 7, idx = bid >> 3;
        bid = (xcd < 4) ? (xcd * 63 + idx) : (252 + (xcd - 4) * 62 + idx);
    }
    int b = bid / 250;
    int s0 = (bid % 250) * 256;

    int wv = t >> 6, lane = t & 63;
    int n31 = lane & 31, kg = lane >> 5;

    // gll source offsets (fixed across taps): chunk k = wv + 4*i
    int goff[5];
#pragma unroll
    for (int i = 0; i < 5; i++) {
        int k = wv + 4 * i;
        if (k < 18) {
            int u = k * 64 + lane;
            int row = u % 96, blk = u / 96;
            goff[i] = row * 192 + (blk >> 1) * 32 + (blk & 1) * 16;
        }
    }
    // issue tap-0 A stage into buf 0 (drained by the barrier below)
    {
        const char* src = (const char*)wf;
#pragma unroll
        for (int i = 0; i < 5; i++) {
            int k = wv + 4 * i;
            if (k < 18) gll16(src + goff[i], Ab + k * 1024);
        }
    }

    // adh[kd*3+kh][nl] = wrapped (d,h) byte offset for s-local nl (t covers 256)
    {
        int s = s0 + t;
        int d = s / 1600, rr = s - d * 1600;
        int h = rr / 40;
#pragma unroll
        for (int kd = 0; kd < 3; kd++) {
            int dd = d + kd - 1; if (dd < 0) dd += 40; else if (dd >= 40) dd -= 40;
#pragma unroll
            for (int kh = 0; kh < 3; kh++) {
                int hh = h + kh - 1; if (hh < 0) hh += 40; else if (hh >= 40) hh -= 40;
                adh[(kd * 3 + kh) * 256 + t] = dd * 307200 + hh * 7680;
            }
        }
    }
    if (t < 96) bsh[t] = bias[t];

    // per-lane w for its two B-rows (nt=0,1)
    int r0s = s0 + wv * 64 + n31;
    int w0 = r0s % 40;
    int w1 = (r0s + 32) % 40;
    __syncthreads();   // adh ready AND tap-0 A landed (barrier drains vmcnt)

    const char* inb = (const char*)(in_t + (size_t)b * 64000 * 96) + kg * 16;

    floatx16 acc[3][2];
#pragma unroll
    for (int mt = 0; mt < 3; mt++)
#pragma unroll
        for (int nt = 0; nt < 2; nt++)
#pragma unroll
            for (int r = 0; r < 16; r++) acc[mt][nt][r] = 0.f;

    for (int tap = 0; tap < 27; tap++) {
        int cur = tap & 1;
        if (tap < 26) {   // prefetch next tap's A straight into the other buffer
            const char* src = (const char*)wf + (tap + 1) * 18432;
            char* dstb = Ab + (cur ^ 1) * 18432;
#pragma unroll
            for (int i = 0; i < 5; i++) {
                int k = wv + 4 * i;
                if (k < 18) gll16(src + goff[i], dstb + k * 1024);
            }
        }
        int kdh = tap / 3, kw = tap - kdh * 3;
        int a0 = adh[kdh * 256 + wv * 64 + n31];
        int a1 = adh[kdh * 256 + wv * 64 + 32 + n31];
        int ww0 = w0 + kw - 1; if (ww0 < 0) ww0 += 40; else if (ww0 >= 40) ww0 -= 40;
        int ww1 = w1 + kw - 1; if (ww1 < 0) ww1 += 40; else if (ww1 >= 40) ww1 -= 40;
        const char* pb0 = inb + a0 + ww0 * 192;
        const char* pb1 = inb + a1 + ww1 * 192;
        const char* Ac = Ab + cur * 18432 + kg * 1536 + n31 * 16;
#pragma unroll
        for (int j = 0; j < 6; j++) {
            half8 b0 = *(const half8*)(pb0 + j * 32);
            half8 b1 = *(const half8*)(pb1 + j * 32);
            const char* Aj = Ac + j * 3072;
            half8 a0f = *(const half8*)(Aj);
            half8 a1f = *(const half8*)(Aj + 512);
            half8 a2f = *(const half8*)(Aj + 1024);
            acc[0][0] = __builtin_amdgcn_mfma_f32_32x32x16_f16(a0f, b0, acc[0][0], 0, 0, 0);
            acc[0][1] = __builtin_amdgcn_mfma_f32_32x32x16_f16(a0f, b1, acc[0][1], 0, 0, 0);
            acc[1][0] = __builtin_amdgcn_mfma_f32_32x32x16_f16(a1f, b0, acc[1][0], 0, 0, 0);
            acc[1][1] = __builtin_amdgcn_mfma_f32_32x32x16_f16(a1f, b1, acc[1][1], 0, 0, 0);
            acc[2][0] = __builtin_amdgcn_mfma_f32_32x32x16_f16(a2f, b0, acc[2][0], 0, 0, 0);
            acc[2][1] = __builtin_amdgcn_mfma_f32_32x32x16_f16(a2f, b1, acc[2][1], 0, 0, 0);
        }
        __syncthreads();   // next-tap A landed; buffers swap
    }

    // epilogue: padded transpose (st overlays adh/Ab only; bsh is outside)
#pragma unroll
    for (int mt = 0; mt < 3; mt++)
#pragma unroll
        for (int nt = 0; nt < 2; nt++)
#pragma unroll
            for (int r = 0; r < 16; r++) {
                int m = mt * 32 + (r & 3) + 8 * (r >> 2) + 4 * kg;
                int sl = wv * 64 + nt * 32 + n31;
                st[sl * 98 + m] = (_Float16)(acc[mt][nt][r] + bsh[m]);
            }
    __syncthreads();

    unsigned int* dst = (unsigned int*)(c3 + ((size_t)(b * 64000 + s0)) * 96);
    for (int i = t; i < 12288; i += 256) {
        int row = i / 48, sg = i % 48;
        dst[i] = *(const unsigned int*)&st[row * 98 + sg * 2];
    }
}

// ---------------- per-(b,c) stats over f16 [b][s][96]: atomic partial sums ----------------
__global__ __launch_bounds__(192) void k_stats_sc(const _Float16* __restrict__ in,
                                                  float* __restrict__ raw) {   // [192][2]
    __shared__ float red_s[16][96], red_q[16][96];
    int bid = blockIdx.x;            // 100 blocks: b = bid/50, chunk of 1280 s
    int b = bid / 50, ch = bid % 50;
    int t = threadIdx.x;
    int sp = t / 12, cs = t % 12;
    const uint4* base = (const uint4*)(in + ((size_t)(b * 64000 + ch * 1280)) * 96);
    float s8[8], q8[8];
#pragma unroll
    for (int e = 0; e < 8; e++) { s8[e] = 0.f; q8[e] = 0.f; }
    for (int i = 0; i < 80; i++) {
        uint4 v = base[(sp + i * 16) * 12 + cs];
        half8 h = __builtin_bit_cast(half8, v);
#pragma unroll
        for (int e = 0; e < 8; e++) { float f = (float)h[e]; s8[e] += f; q8[e] += f * f; }
    }
#pragma unroll
    for (int e = 0; e < 8; e++) { red_s[sp][cs * 8 + e] = s8[e]; red_q[sp][cs * 8 + e] = q8[e]; }
    __syncthreads();
    if (t < 96) {
        float S = 0.f, Q = 0.f;
        for (int k = 0; k < 16; k++) { S += red_s[k][t]; Q += red_q[k][t]; }
        atomicAdd(&raw[(b * 96 + t) * 2], S);
        atomicAdd(&raw[(b * 96 + t) * 2 + 1], Q);
    }
}

// ---------------- norm + exact gelu on f16 [b][s][96], in-place; finalize fused ----------------
__global__ __launch_bounds__(256) void k_ng16(_Float16* __restrict__ x, const float* __restrict__ raw) {
    __shared__ float2 sfs[192];
    int t = threadIdx.x, bid = blockIdx.x;
    if (t < 192) {
        float S = raw[t * 2], Q = raw[t * 2 + 1];
        float mu = S * (1.f / 64000.f);
        float var = Q * (1.f / 64000.f) - mu * mu;
        sfs[t] = make_float2(mu, rsqrtf(var + 1e-5f));
    }
    __syncthreads();
    uint4* p = (uint4*)x;
#pragma unroll
    for (int k = 0; k < 4; k++) {
        int i = bid * 1024 + k * 256 + t;      // uint4 index, 1,536,000 total
        int e0 = i * 8;
        int b = e0 / 6144000;
        int c0 = e0 % 96;
        const float2* sp = &sfs[b * 96 + c0];
        uint4 v = p[i];
        half8 h = __builtin_bit_cast(half8, v);
        _Float16 o[8];
#pragma unroll
        for (int e = 0; e < 8; e++) {
            float2 st = sp[e];
            float u = ((float)h[e] - st.x) * st.y;
            o[e] = (_Float16)(0.5f * u * (1.f + erff(u * 0.70710678118654752f)));
        }
        p[i] = *(uint4*)o;
    }
}

// ---------------- 96x96 f16 MFMA GEMM on [b][s][96]; MODE 1: sigmoid * x epilogue ----------------
template <int MODE>
__global__ __launch_bounds__(256) void k_gemm96(const _Float16* __restrict__ in,
                                                const _Float16* __restrict__ w,   // [96][96]
                                                const float* __restrict__ bias,
                                                const float* __restrict__ xg,     // [b][c][s] f32 (MODE 1)
                                                _Float16* __restrict__ outp) {
    __shared__ _Float16 un[12544];   // union: W (9216) | out staging 128 x 98
    __shared__ float bias_s[96];
    int t = threadIdx.x, bid = blockIdx.x;
    { int xcd = bid & 7; bid = xcd * 125 + (bid >> 3); }   // chain conv3's XCD map
    int b = bid / 500, s0 = (bid % 500) * 128;
    for (int i = t; i < 1152; i += 256) ((uint4*)un)[i] = ((const uint4*)w)[i];
    if (t < 96) bias_s[t] = bias[t];
    __syncthreads();

    int ws = t >> 6, lane = t & 63;
    int n = lane & 31, kg = lane >> 5;
    int p = ws * 32 + n;
    const uint4* brow = (const uint4*)(in + ((size_t)(b * 64000 + s0 + p)) * 96);
    uint4 bf[6];
#pragma unroll
    for (int kc = 0; kc < 6; kc++) bf[kc] = brow[kc * 2 + kg];

    floatx16 acc[3];
#pragma unroll
    for (int mt = 0; mt < 3; mt++)
#pragma unroll
        for (int r = 0; r < 16; r++) acc[mt][r] = 0.f;
#pragma unroll
    for (int kc = 0; kc < 6; kc++) {
        half8 bfh = __builtin_bit_cast(half8, bf[kc]);
#pragma unroll
        for (int mt = 0; mt < 3; mt++) {
            uint4 au = *(const uint4*)&un[(mt * 32 + n) * 96 + kc * 16 + kg * 8];
            acc[mt] = __builtin_amdgcn_mfma_f32_32x32x16_f16(__builtin_bit_cast(half8, au), bfh, acc[mt], 0, 0, 0);
        }
    }
    __syncthreads();   // done reading W; un becomes output staging

#pragma unroll
    for (int mt = 0; mt < 3; mt++)
#pragma unroll
        for (int r = 0; r < 16; r++) {
            int m = mt * 32 + (r & 3) + 8 * (r >> 2) + 4 * kg;
            int sl = ws * 32 + n;
            float v = acc[mt][r] + bias_s[m];
            if (MODE == 1) {
                v = 1.f / (1.f + __expf(-v));
                v *= xg[((size_t)(b * 96 + m)) * 64000 + s0 + sl];
            }
            un[sl * 98 + m] = (_Float16)v;
        }
    __syncthreads();

    unsigned int* dst = (unsigned int*)(outp + ((size_t)(b * 64000 + s0)) * 96);
    for (int i = t; i < 6144; i += 256) {
        int row = i / 48, sg = i % 48;
        dst[i] = *(const unsigned int*)&un[row * 98 + sg * 2];
    }
}

// ---------------- qkv GEMM (ONCE): qA[b][s][288] f16, natural s-order ----------------
__global__ __launch_bounds__(256) void k_qkv(const _Float16* __restrict__ xt,
                                             const _Float16* __restrict__ wq,  // [288][96]
                                             const float* __restrict__ qb,
                                             _Float16* __restrict__ qA) {
    __shared__ _Float16 smem[27648];   // union: A (288x96) then epi (64 x 296)
    __shared__ float bias_s[288];
    int t = threadIdx.x;
    int bid = blockIdx.x;
    { int xcd = bid & 7; bid = xcd * 125 + (bid >> 3); }   // chain conv3's XCD map
    int b = bid / 500;
    int s0 = (bid % 500) * 128;

    for (int i = t; i < 3456; i += 256) ((uint4*)smem)[i] = ((const uint4*)wq)[i];
    for (int i = t; i < 288; i += 256) bias_s[i] = qb[i];
    __syncthreads();

    int ws = t >> 6, lane = t & 63;
    int n = lane & 31, kg = lane >> 5;
    int p = ws * 32 + n;

    const uint4* brow = (const uint4*)(xt + ((size_t)(b * 64000 + s0 + p)) * 96);
    uint4 bf[6];
#pragma unroll
    for (int kc = 0; kc < 6; kc++) bf[kc] = brow[kc * 2 + kg];

    floatx16 acc[9];
#pragma unroll
    for (int mt = 0; mt < 9; mt++)
#pragma unroll
        for (int r = 0; r < 16; r++) acc[mt][r] = 0.f;

#pragma unroll
    for (int kc = 0; kc < 6; kc++) {
        half8 bfh = __builtin_bit_cast(half8, bf[kc]);
#pragma unroll
        for (int mt = 0; mt < 9; mt++) {
            uint4 au = *(const uint4*)&smem[(mt * 32 + n) * 96 + kc * 16 + kg * 8];
            acc[mt] = __builtin_amdgcn_mfma_f32_32x32x16_f16(__builtin_bit_cast(half8, au), bfh, acc[mt], 0, 0, 0);
        }
    }

    const float scale = 0.20412414523193154f;
    for (int q = 0; q < 2; q++) {
        __syncthreads();
        if ((ws >> 1) == q) {
            int pl = (ws & 1) * 32 + n;
#pragma unroll
            for (int mt = 0; mt < 9; mt++)
#pragma unroll
                for (int g = 0; g < 4; g++) {
                    int m0 = mt * 32 + g * 8 + kg * 4;
                    _Float16 tm[4];
#pragma unroll
                    for (int j = 0; j < 4; j++) {
                        float v = acc[mt][g * 4 + j] + bias_s[m0 + j];
                        if (m0 + j < 96) v *= scale;
                        tm[j] = (_Float16)v;
                    }
                    *(uint2*)&smem[pl * 296 + m0] = *(uint2*)tm;
                }
        }
        __syncthreads();
        for (int idx = t; idx < 2304; idx += 256) {
            int pl = idx / 36, seg = idx % 36;
            int s = s0 + q * 64 + pl;
            uint4 v = *(const uint4*)&smem[pl * 296 + seg * 8];
            *(uint4*)&qA[((size_t)(b * 64000 + s)) * 288 + seg * 8] = v;
        }
    }
}

// ---------------- fused axial attention: softmax + PV, sum into osum[b][s][96] ----------------
// block=320: 2 lines x (4 heads x 40 queries), one query/thread.
template <int AXIS, bool ACC>
__global__ __launch_bounds__(320, 3) void k_attn(const _Float16* __restrict__ qA,
                                                 _Float16* __restrict__ osum) {
    __shared__ _Float16 kk[8352];     // k: [line][key][96]; then out staging [line][l][104]
    __shared__ _Float16 vT[7744];     // plane lh=line*4+head, stride 968: [hd][40 keys]
    int t = threadIdx.x;
    int bid = blockIdx.x;
    bid = (bid & 7) * 200 + (bid >> 3);   // bijective XCD chunking (1600%8==0)
    int b = bid / 800;
    int r0 = (bid % 800) * 2;

    auto smap = [&](int r, int l) -> int {
        if (AXIS == 0) return l * 1600 + r;
        else if (AXIS == 1) { int d = r / 40, w = r % 40; return d * 1600 + l * 40 + w; }
        else return r * 40 + l;
    };
    const uint4* src = (const uint4*)qA;
    for (int i = t; i < 960; i += 320) {
        int line = i / 480, key = (i % 480) / 12, seg = i % 12;
        int row = b * 64000 + smap(r0 + line, key);
        ((uint4*)kk)[i] = src[(size_t)row * 36 + 12 + seg];
    }
    for (int i = t; i < 960; i += 320) {
        int line = i / 480, key = (i % 480) / 12, seg = i % 12;
        int row = b * 64000 + smap(r0 + line, key);
        uint4 v = src[(size_t)row * 36 + 24 + seg];
        _Float16 tmp[8];
        *(uint4*)tmp = v;
#pragma unroll
        for (int e = 0; e < 8; e++) {
            int hdg = seg * 8 + e;
            vT[(line * 4 + hdg / 24) * 968 + (hdg % 24) * 40 + key] = tmp[e];
        }
    }

    int line = t / 160, head = (t % 160) / 40, ql = t % 40;
    int rr = r0 + line;
    unsigned int qu[12];
    {
        const uint4* qp = (const uint4*)(qA + ((size_t)(b * 64000 + smap(rr, ql))) * 288 + head * 24);
#pragma unroll
        for (int j = 0; j < 3; j++) *(uint4*)&qu[j * 4] = qp[j];
    }
    __syncthreads();

    float s[40];
    const uint4* kbase = (const uint4*)kk + line * 480 + head * 3;
#pragma unroll 4
    for (int key = 0; key < 40; key++) {
        unsigned int kku[12];
#pragma unroll
        for (int j = 0; j < 3; j++) *(uint4*)&kku[j * 4] = kbase[key * 12 + j];
        float a = 0.f;
#pragma unroll
        for (int i = 0; i < 12; i++) a = fdot2(kku[i], qu[i], a);
        s[key] = a;
    }

    float mx = -1e30f;
#pragma unroll
    for (int i = 0; i < 40; i++) mx = fmaxf(mx, s[i]);
    float sum = 0.f;
#pragma unroll
    for (int i = 0; i < 40; i++) { s[i] = __expf(s[i] - mx); sum += s[i]; }
    float inv = 1.f / sum;

    unsigned int pw[20];
#pragma unroll
    for (int i = 0; i < 20; i++) {
        half2 a = { (_Float16)(s[2 * i] * inv), (_Float16)(s[2 * i + 1] * inv) };
        pw[i] = __builtin_bit_cast(unsigned int, a);
    }

    __syncthreads();   // kk becomes output staging

    float o[24];
    const uint4* vbase = (const uint4*)vT + (line * 4 + head) * 121;
#pragma unroll 2
    for (int hd = 0; hd < 24; hd++) {
        unsigned int vv[20];
#pragma unroll
        for (int j = 0; j < 5; j++) *(uint4*)&vv[j * 4] = vbase[hd * 5 + j];
        float a = 0.f;
#pragma unroll
        for (int i = 0; i < 20; i++) a = fdot2(vv[i], pw[i], a);
        o[hd] = a;
    }

    {
        _Float16 tm[24];
#pragma unroll
        for (int j = 0; j < 24; j++) tm[j] = (_Float16)o[j];
        _Float16* dA = &kk[(line * 40 + ql) * 104 + head * 24];
#pragma unroll
        for (int j = 0; j < 3; j++) ((uint4*)dA)[j] = ((uint4*)tm)[j];
    }
    __syncthreads();

    // flush 80 rows x 96 f16 to osum[smap(r,l)] (192B rows; contiguous for AXIS 2)
    uint4* dst = (uint4*)osum;
    for (int i = t; i < 960; i += 320) {
        int row = i / 12, seg = i % 12;
        int s2 = smap(r0 + row / 40, row % 40);
        size_t di = ((size_t)(b * 64000 + s2)) * 12 + seg;
        uint4 v = *(const uint4*)&kk[row * 104 + seg * 8];
        if (ACC) {
            half8 a = __builtin_bit_cast(half8, dst[di]);
            half8 c = __builtin_bit_cast(half8, v);
            dst[di] = __builtin_bit_cast(uint4, a + c);
        } else {
            dst[di] = v;
        }
    }
}

// ---------------- proj GEMM: out[b][c][s] = proj_w @ osum[b][s][96] + pb ----------------
__global__ __launch_bounds__(256) void k_proj(const _Float16* __restrict__ osum,
                                              const _Float16* __restrict__ wp,  // [96][96]
                                              const float* __restrict__ pb,
                                              float* __restrict__ out) {
    __shared__ _Float16 A[9216];
    __shared__ float bias_s[96];
    int t = threadIdx.x;
    int bid = blockIdx.x;
    int b = bid / 500;
    int s0 = (bid % 500) * 128;
    for (int i = t; i < 1152; i += 256) ((uint4*)A)[i] = ((const uint4*)wp)[i];
    if (t < 96) bias_s[t] = pb[t];
    __syncthreads();

    int ws = t >> 6, lane = t & 63;
    int n = lane & 31, kg = lane >> 5;
    int s = s0 + ws * 32 + n;

    const uint4* brow = (const uint4*)(osum + ((size_t)(b * 64000 + s0 + ws * 32 + n)) * 96);
    uint4 bf[6];
#pragma unroll
    for (int kc = 0; kc < 6; kc++) bf[kc] = brow[kc * 2 + kg];

    floatx16 acc[3];
#pragma unroll
    for (int mt = 0; mt < 3; mt++)
#pragma unroll
        for (int r = 0; r < 16; r++) acc[mt][r] = 0.f;

#pragma unroll
    for (int kc = 0; kc < 6; kc++) {
        half8 bfh = __builtin_bit_cast(half8, bf[kc]);
#pragma unroll
        for (int mt = 0; mt < 3; mt++) {
            uint4 au = *(const uint4*)&A[(mt * 32 + n) * 96 + kc * 16 + kg * 8];
            acc[mt] = __builtin_amdgcn_mfma_f32_32x32x16_f16(__builtin_bit_cast(half8, au), bfh, acc[mt], 0, 0, 0);
        }
    }

#pragma unroll
    for (int mt = 0; mt < 3; mt++)
#pragma unroll
        for (int r = 0; r < 16; r++) {
            int m = mt * 32 + (r & 3) + 8 * (r >> 2) + 4 * kg;
            out[((size_t)(b * 96 + m)) * 64000 + s] = acc[mt][r] + bias_s[m];
        }
}

extern "C" void kernel_launch(void* const* d_in, const int* in_sizes, int n_in,
                              void* d_out, int out_size, void* d_ws, size_t ws_size,
                              hipStream_t stream) {
    const float* x      = (const float*)d_in[0];
    const float* pos    = (const float*)d_in[1];
    const float* qkv_w  = (const float*)d_in[2];
    const float* qkv_b  = (const float*)d_in[3];
    const float* lp1_w  = (const float*)d_in[4];
    const float* lp1_b  = (const float*)d_in[5];
    const float* lp2_w  = (const float*)d_in[6];
    const float* lp2_b  = (const float*)d_in[7];
    const float* mod1_w = (const float*)d_in[8];
    const float* mod1_b = (const float*)d_in[9];
    const float* mod2_w = (const float*)d_in[10];
    const float* mod2_b = (const float*)d_in[11];
    // d_in[12..16]: pa_w, pa_b, R6_d, R6_h, R6_w — provably no-ops (see header)
    const float* proj_w = (const float*)d_in[17];
    const float* proj_b = (const float*)d_in[18];
    float* out = (float*)d_out;
    float* ws = (float*)d_ws;

    // f16 buffers (sizes in f32-float units of ws):
    _Float16* bufA = (_Float16*)ws;                        // 12.288M f16: c3/B0 -> xm
    _Float16* bufB = (_Float16*)(ws + 6144000);            // 12.288M f16: C2/D -> osum
    _Float16* qA   = (_Float16*)(ws + 12288000);           // 36.864M f16
    _Float16* in_t = qA;                                   // pos f16 [s][c], dead before qkv
    _Float16* wf   = (_Float16*)(ws + 30720000);           // 248,832 f16
    _Float16* wq   = (_Float16*)(ws + 30844416);           // 27,648 f16
    _Float16* wpj  = (_Float16*)(ws + 30858240);           // 9,216 f16
    _Float16* wfold= (_Float16*)(ws + 30862848);           // 9,216 f16
    _Float16* wm2  = (_Float16*)(ws + 30867456);           // 9,216 f16
    float* bfold   = ws + 30872064;                        // 96 f32
    float* raw     = ws + 30872160;                        // 768 f32 (raw0 | raw1)
    float* raw0 = raw, *raw1 = raw + 384;

    k_cvt_in<<<2016, 256, 0, stream>>>(pos, in_t);
    k_cvt_w<<<972, 256, 0, stream>>>(lp1_w, wf, raw);     // block 0 zeroes raw
    k_fold<<<36, 256, 0, stream>>>(lp2_w, lp2_b, mod1_w, mod1_b, wfold, bfold);
    k_cvt_f16<<<36, 256, 0, stream>>>(mod2_w, wm2, 9216);
    k_cvt_f16<<<108, 256, 0, stream>>>(qkv_w, wq, 27648);
    k_cvt_f16<<<36, 256, 0, stream>>>(proj_w, wpj, 9216);

    // c3 = conv3(pos)  [f16, [b][s][96]]
    k_conv3_v8<<<500, 256, 0, stream>>>(in_t, wf, lp1_b, bufA);
    // B0 = gelu(IN(c3)) in-place (finalize fused into ng16)
    k_stats_sc<<<100, 192, 0, stream>>>(bufA, raw0);
    k_ng16<<<1500, 256, 0, stream>>>(bufA, raw0);
    // C2 = W' @ B0 + b'   (folded lp2 -> mod1)
    k_gemm96<0><<<1000, 256, 0, stream>>>(bufA, wfold, bfold, nullptr, bufB);
    // D = gelu(IN(C2)) in-place
    k_stats_sc<<<100, 192, 0, stream>>>(bufB, raw1);
    k_ng16<<<1500, 256, 0, stream>>>(bufB, raw1);
    // xm = x * sigmoid(mod2 @ D + b)   [f16 [b][s][96], into bufA (B0 dead)]
    k_gemm96<1><<<1000, 256, 0, stream>>>(bufB, wm2, mod2_b, x, bufA);

    // qkv ONCE (s-order); qA overwrites in_t (dead)
    k_qkv<<<1000, 256, 0, stream>>>(bufA, wq, qkv_b, qA);
    // attention: axis 2 writes osum (contiguous), axes 0/1 accumulate (192B-row RMW)
    k_attn<2, false><<<1600, 320, 0, stream>>>(qA, bufB);
    k_attn<0, true ><<<1600, 320, 0, stream>>>(qA, bufB);
    k_attn<1, true ><<<1600, 320, 0, stream>>>(qA, bufB);

    // out = proj(osum)
    k_proj<<<1000, 256, 0, stream>>>(bufB, wpj, proj_b, out);
}